// Round 3
// baseline (947.816 us; speedup 1.0000x reference)
//
#include <hip/hip_runtime.h>

// LatticeSuperpixel: B=8, C=20, H=W=512, 32x32 seeds, 16x16 cells, 4 levels.
//
// R2 design (resubmit — previous run died on container acquire, not kernel):
//  - k_iter has NO x staging in LDS. Phase 1 loads each pixel's 20 channels
//    global->reg (coalesced 64B segments); phase 2 re-reads the 21KB tile
//    from global (L1/L2-hot). LDS = qs only (9.2 KB) -> 8 blocks/CU.
//  - Phase 2 runs on ALL 4 waves (wave w owns pixel-strips {2w,2w+1}),
//    per-wave shfl fold, direct atomics (756/block). No single-wave tail.
//  - One barrier per k_iter block (was 2-3).
//  - Seeds + norms via the scalar path (block-uniform indices, s_load).
//  - XCD-aware cell swizzle (k_iter: atomic L2 locality; k_final: write-merge
//    of adjacent cells' 64B half-lines in the same XCD L2).
#define NB 8
#define NC 20
#define NH 512
#define NW 512
#define NS 1024           // 32*32 seeds
#define HW (NH * NW)
#define SEEDS_ELEMS (NB * NS * NC)   // 163840
#define DENOM_ELEMS (NB * NS)        // 8192
#define EPSF 1e-8f

static constexpr int DYO[9] = {-1, -1, -1, 0, 0, 0, 1, 1, 1};
static constexpr int DXO[9] = {-1, 0, 1, -1, 0, 1, -1, 0, 1};

__device__ __forceinline__ int clampi(int v, int lo, int hi) {
    return v < lo ? lo : (v > hi ? hi : v);
}

// 1024 cells -> 128 consecutive cells per XCD (bijective).
__device__ __forceinline__ int xcd_cell(int bx) {
    return ((bx & 7) << 7) + (bx >> 3);
}

// ---------------------------------------------------------------------------
// Kernel 1: seed init = mean over each 16x16 patch, per channel + seed norm.
// ---------------------------------------------------------------------------
__global__ __launch_bounds__(160) void k_seed_init(const float* __restrict__ x,
                                                   float* __restrict__ seeds,
                                                   float* __restrict__ snorm) {
    __shared__ float sm[NC];
    const int tt = threadIdx.x;           // < 160
    const int cell = blockIdx.x;
    const int b = blockIdx.y;
    const int cy = cell >> 5, cx = cell & 31;
    const int c = tt >> 3, s = tt & 7;

    const float* xb = x + (size_t)b * (NC * HW) + (size_t)c * HW
                        + (size_t)(cy << 4) * NW + (cx << 4);
    float acc = 0.f;
#pragma unroll
    for (int k = 0; k < 8; ++k) {
        const int row = (k << 1) + (s >> 2);
        const int col = (s & 3) << 2;
        const float4 v = *reinterpret_cast<const float4*>(xb + row * NW + col);
        acc += v.x + v.y + v.z + v.w;
    }
    acc += __shfl_xor(acc, 1, 64);
    acc += __shfl_xor(acc, 2, 64);
    acc += __shfl_xor(acc, 4, 64);
    if (s == 0) {
        const float mv = acc * (1.0f / 256.0f);
        seeds[((size_t)(b << 10) + cell) * NC + c] = mv;
        sm[c] = mv;
    }
    __syncthreads();
    if (tt == 0) {
        float n = 0.f;
#pragma unroll
        for (int cc = 0; cc < NC; ++cc) n += sm[cc] * sm[cc];
        snorm[(b << 10) + cell] = n;
    }
}

// ---------------------------------------------------------------------------
// Kernel 2: one assignment iteration + seed-update accumulation.
// Phase 1: 256 thr = 1 pixel: 20 global dword loads (own channels), dist vs
//          9 seeds (scalar-path seed loads), softmax -> qs (LDS, 9.2 KB).
// Phase 2: all 4 waves; wave w owns pixel-strips {2w, 2w+1}. Thread
//          (cg<7, s<8): channels {3cg..3cg+2} (c==20 -> denom ones),
//          x from global (L1/L2-hot), q from LDS (conflict-free b128),
//          fold s via shfl, 27 atomics per s==0 lane (756/block).
// ---------------------------------------------------------------------------
__global__ __launch_bounds__(256, 8) void k_iter(const float* __restrict__ x,
                                                 const float* __restrict__ seeds,
                                                 const float* __restrict__ snorm,
                                                 float* __restrict__ numer,
                                                 float* __restrict__ denom) {
    __shared__ __align__(16) float qs[9 * 256];   // [offset][pixel] 9.2 KB

    const int t = threadIdx.x;
    const int cell = xcd_cell(blockIdx.x);
    const int b = blockIdx.y;
    const int cy = cell >> 5, cx = cell & 31;

    const float* xb = x + (size_t)b * (NC * HW) + (size_t)(cy << 4) * NW + (cx << 4);

    // ---- phase 1: own pixel's 20 channels global -> reg ----
    const float* xp = xb + (t >> 4) * NW + (t & 15);
    float xv[NC];
#pragma unroll
    for (int c = 0; c < NC; ++c) xv[c] = xp[(size_t)c * HW];

    // block-uniform neighbor-seed indices -> SGPR
    int nidx[9];
#pragma unroll
    for (int o = 0; o < 9; ++o) {
        const int ny = clampi(cy + DYO[o], 0, 31);
        const int nx = clampi(cx + DXO[o], 0, 31);
        nidx[o] = __builtin_amdgcn_readfirstlane((b << 10) + (ny << 5) + nx);
    }

    float d[9];
#pragma unroll
    for (int o = 0; o < 9; ++o) {
        const float* sp = seeds + (size_t)nidx[o] * NC;  // uniform -> s_load
        float ip = 0.f;
#pragma unroll
        for (int c = 0; c < NC; ++c) ip += xv[c] * sp[c];
        d[o] = snorm[nidx[o]] - 2.0f * ip;
    }
    float m = d[0];
#pragma unroll
    for (int o = 1; o < 9; ++o) m = fminf(m, d[o]);
    float w[9];
    float wsum = 0.f;
#pragma unroll
    for (int o = 0; o < 9; ++o) {
        w[o] = __expf(m - d[o]);
        wsum += w[o];
    }
    const float inv = 1.0f / wsum;
#pragma unroll
    for (int o = 0; o < 9; ++o) qs[(o << 8) + t] = w[o] * inv;
    __syncthreads();

    // ---- phase 2: all 4 waves, register-tiled 21x9 reduction ----
    const int wid = t >> 6, tl = t & 63;
    if (tl < 56) {
        const int cg = tl >> 3, s = tl & 7;
        const int r0 = cg * 3;
        float acc[3][9];
#pragma unroll
        for (int j = 0; j < 3; ++j)
#pragma unroll
            for (int o = 0; o < 9; ++o) acc[j][o] = 0.f;

#pragma unroll
        for (int kk = 0; kk < 2; ++kk) {
            const int q = (((wid << 1) + kk) << 3) + s;   // quad id 0..63
            const float* xr = xb + (q >> 2) * NW + ((q & 3) << 2);
            const float4 x0 = *reinterpret_cast<const float4*>(xr + (size_t)(r0 + 0) * HW);
            const float4 x1 = *reinterpret_cast<const float4*>(xr + (size_t)(r0 + 1) * HW);
            float4 x2 = make_float4(1.f, 1.f, 1.f, 1.f);
            if (cg < 6)
                x2 = *reinterpret_cast<const float4*>(xr + (size_t)(r0 + 2) * HW);
#pragma unroll
            for (int o = 0; o < 9; ++o) {
                const float4 q4 = *reinterpret_cast<const float4*>(&qs[(o << 8) + (q << 2)]);
                acc[0][o] += q4.x * x0.x + q4.y * x0.y + q4.z * x0.z + q4.w * x0.w;
                acc[1][o] += q4.x * x1.x + q4.y * x1.y + q4.z * x1.z + q4.w * x1.w;
                acc[2][o] += q4.x * x2.x + q4.y * x2.y + q4.z * x2.z + q4.w * x2.w;
            }
        }
        // fold the 8 strips (s = lane bits 0..2)
#pragma unroll
        for (int j = 0; j < 3; ++j)
#pragma unroll
            for (int o = 0; o < 9; ++o) {
                acc[j][o] += __shfl_xor(acc[j][o], 1, 64);
                acc[j][o] += __shfl_xor(acc[j][o], 2, 64);
                acc[j][o] += __shfl_xor(acc[j][o], 4, 64);
            }
        if (s == 0) {
#pragma unroll
            for (int o = 0; o < 9; ++o) {
                const size_t sb = (size_t)nidx[o];
#pragma unroll
                for (int j = 0; j < 3; ++j) {
                    const int c = r0 + j;
                    if (c < NC) atomicAdd(&numer[sb * NC + c], acc[j][o]);
                    else        atomicAdd(&denom[sb], acc[j][o]);
                }
            }
        }
    }
}

// ---------------------------------------------------------------------------
// Kernel 3: seeds = numer/(denom+eps), re-zero numer/denom, seed norms.
// ---------------------------------------------------------------------------
__global__ __launch_bounds__(160) void k_divz(float* __restrict__ seeds,
                                              float* __restrict__ snorm,
                                              float* __restrict__ numer,
                                              float* __restrict__ denom) {
    __shared__ float sq[160];
    const int t = threadIdx.x;
    const int gidx = blockIdx.x * 160 + t;
    const int sid = blockIdx.x * 8 + t / 20;
    const float v = numer[gidx] / (denom[sid] + EPSF);
    seeds[gidx] = v;
    numer[gidx] = 0.f;
    sq[t] = v * v;
    __syncthreads();
    if (t < 8) {
        const int ss = blockIdx.x * 8 + t;
        float n = 0.f;
#pragma unroll
        for (int c = 0; c < NC; ++c) n += sq[t * 20 + c];
        snorm[ss] = n;
        denom[ss] = 0.f;
    }
}

// ---------------------------------------------------------------------------
// Kernel 4: final assignment pass -> write Q (B, 9, H, W). No LDS, no barriers.
// ---------------------------------------------------------------------------
__global__ __launch_bounds__(256, 8) void k_final(const float* __restrict__ x,
                                                  const float* __restrict__ seeds,
                                                  const float* __restrict__ snorm,
                                                  float* __restrict__ out) {
    const int t = threadIdx.x;
    const int cell = xcd_cell(blockIdx.x);
    const int b = blockIdx.y;
    const int cy = cell >> 5, cx = cell & 31;

    const int py = (cy << 4) + (t >> 4);
    const int px = (cx << 4) + (t & 15);
    const float* xp = x + (size_t)b * (NC * HW) + (size_t)py * NW + px;
    float xv[NC];
#pragma unroll
    for (int c = 0; c < NC; ++c) xv[c] = xp[(size_t)c * HW];

    float d[9];
#pragma unroll
    for (int o = 0; o < 9; ++o) {
        const int ny = clampi(cy + DYO[o], 0, 31);
        const int nx = clampi(cx + DXO[o], 0, 31);
        const int si = __builtin_amdgcn_readfirstlane((b << 10) + (ny << 5) + nx);
        const float* sp = seeds + (size_t)si * NC;  // uniform -> s_load
        float ip = 0.f;
#pragma unroll
        for (int c = 0; c < NC; ++c) ip += xv[c] * sp[c];
        d[o] = snorm[si] - 2.0f * ip;
    }
    float m = d[0];
#pragma unroll
    for (int o = 1; o < 9; ++o) m = fminf(m, d[o]);
    float w[9];
    float wsum = 0.f;
#pragma unroll
    for (int o = 0; o < 9; ++o) {
        w[o] = __expf(m - d[o]);
        wsum += w[o];
    }
    const float inv = 1.0f / wsum;
#pragma unroll
    for (int o = 0; o < 9; ++o) {
        out[(((size_t)b * 9 + o) * NH + py) * NW + px] = w[o] * inv;
    }
}

// ---------------------------------------------------------------------------
extern "C" void kernel_launch(void* const* d_in, const int* in_sizes, int n_in,
                              void* d_out, int out_size, void* d_ws, size_t ws_size,
                              hipStream_t stream) {
    const float* x = (const float*)d_in[0];
    float* out = (float*)d_out;

    float* seeds = (float*)d_ws;                 // 163840 floats
    float* numer = seeds + SEEDS_ELEMS;          // 163840 floats
    float* denom = numer + SEEDS_ELEMS;          // 8192 floats
    float* snorm = denom + DENOM_ELEMS;          // 8192 floats

    // one-time zero of the accumulators (k_divz re-zeros between iterations)
    hipMemsetAsync(numer, 0, (SEEDS_ELEMS + DENOM_ELEMS) * sizeof(float), stream);

    const dim3 grid(NS, NB);  // 1024 cells x 8 batches
    k_seed_init<<<grid, 160, 0, stream>>>(x, seeds, snorm);

    for (int it = 0; it < 3; ++it) {
        k_iter<<<grid, 256, 0, stream>>>(x, seeds, snorm, numer, denom);
        k_divz<<<SEEDS_ELEMS / 160, 160, 0, stream>>>(seeds, snorm, numer, denom);
    }
    k_final<<<grid, 256, 0, stream>>>(x, seeds, snorm, out);
}

// Round 4
// 646.269 us; speedup vs baseline: 1.4666x; 1.4666x over previous
//
#include <hip/hip_runtime.h>

// LatticeSuperpixel: B=8, C=20, H=W=512, 32x32 seeds, 16x16 cells, 4 levels.
//
// R3 design: ZERO global atomics.
//  R2 post-mortem: 756 atomics/block -> 6.2M device-scope atomics = HBM-side
//  RMW (WRITE_SIZE 23->142 MB, k_iter 100->243 us). Fix: each (cell,offset)
//  partial targets exactly ONE seed, and every seed receives exactly 9
//  (cell,offset) pairs (3 per axis even at clamped edges). So:
//   - k_iter writes its 189 partials (21 ch x 9 off, ch20 = denom ones-row)
//     as one contiguous 756B non-atomic burst to part[cell][9][21].
//     Cross-wave combine via 3.5 KB LDS pbuf. No memsets needed at all.
//   - k_divz gathers the fixed 9-entry stencil per seed, divides, writes
//     seeds + snorm.
//  Kept from R2: no x staging in LDS (phase 2 re-reads global, L2-hot);
//  scalar-path seed loads; 4-wave phase 2; XCD cell swizzle; 9.2 KB qs.
#define NB 8
#define NC 20
#define NH 512
#define NW 512
#define NS 1024           // 32*32 seeds
#define HW (NH * NW)
#define SEEDS_ELEMS (NB * NS * NC)   // 163840
#define SNORM_ELEMS (NB * NS)        // 8192
#define PART_STRIDE 189              // 9 offsets * 21 channels
#define EPSF 1e-8f

static constexpr int DYO[9] = {-1, -1, -1, 0, 0, 0, 1, 1, 1};
static constexpr int DXO[9] = {-1, 0, 1, -1, 0, 1, -1, 0, 1};

__device__ __forceinline__ int clampi(int v, int lo, int hi) {
    return v < lo ? lo : (v > hi ? hi : v);
}

// 1024 cells -> 128 consecutive cells per XCD (bijective).
__device__ __forceinline__ int xcd_cell(int bx) {
    return ((bx & 7) << 7) + (bx >> 3);
}

// ---------------------------------------------------------------------------
// Kernel 1: seed init = mean over each 16x16 patch, per channel + seed norm.
// ---------------------------------------------------------------------------
__global__ __launch_bounds__(160) void k_seed_init(const float* __restrict__ x,
                                                   float* __restrict__ seeds,
                                                   float* __restrict__ snorm) {
    __shared__ float sm[NC];
    const int tt = threadIdx.x;           // < 160
    const int cell = blockIdx.x;
    const int b = blockIdx.y;
    const int cy = cell >> 5, cx = cell & 31;
    const int c = tt >> 3, s = tt & 7;

    const float* xb = x + (size_t)b * (NC * HW) + (size_t)c * HW
                        + (size_t)(cy << 4) * NW + (cx << 4);
    float acc = 0.f;
#pragma unroll
    for (int k = 0; k < 8; ++k) {
        const int row = (k << 1) + (s >> 2);
        const int col = (s & 3) << 2;
        const float4 v = *reinterpret_cast<const float4*>(xb + row * NW + col);
        acc += v.x + v.y + v.z + v.w;
    }
    acc += __shfl_xor(acc, 1, 64);
    acc += __shfl_xor(acc, 2, 64);
    acc += __shfl_xor(acc, 4, 64);
    if (s == 0) {
        const float mv = acc * (1.0f / 256.0f);
        seeds[((size_t)(b << 10) + cell) * NC + c] = mv;
        sm[c] = mv;
    }
    __syncthreads();
    if (tt == 0) {
        float n = 0.f;
#pragma unroll
        for (int cc = 0; cc < NC; ++cc) n += sm[cc] * sm[cc];
        snorm[(b << 10) + cell] = n;
    }
}

// ---------------------------------------------------------------------------
// Kernel 2: one assignment iteration -> per-(cell,offset) partials.
// Phase 1: 256 thr = 1 pixel: 20 global loads, dist vs 9 seeds (scalar-path),
//          softmax -> qs (LDS).
// Phase 2: all 4 waves; wave w owns pixel-strips {2w,2w+1}; thread (cg<7,s<8)
//          = channels {3cg..3cg+2} (c==20 -> ones/denom); shfl fold; per-wave
//          partials -> pbuf (LDS); cross-wave sum; ONE contiguous 756B
//          non-atomic store of part[cell][189]. Zero atomics.
// ---------------------------------------------------------------------------
__global__ __launch_bounds__(256, 8) void k_iter(const float* __restrict__ x,
                                                 const float* __restrict__ seeds,
                                                 const float* __restrict__ snorm,
                                                 float* __restrict__ part) {
    __shared__ __align__(16) float qs[9 * 256];     // [offset][pixel] 9.2 KB
    __shared__ float pbuf[4 * 9 * 24];              // [wave][offset][ch pad24] 3.5 KB

    const int t = threadIdx.x;
    const int cell = xcd_cell(blockIdx.x);
    const int b = blockIdx.y;
    const int cy = cell >> 5, cx = cell & 31;

    const float* xb = x + (size_t)b * (NC * HW) + (size_t)(cy << 4) * NW + (cx << 4);

    // ---- phase 1: own pixel's 20 channels global -> reg ----
    const float* xp = xb + (t >> 4) * NW + (t & 15);
    float xv[NC];
#pragma unroll
    for (int c = 0; c < NC; ++c) xv[c] = xp[(size_t)c * HW];

    float d[9];
#pragma unroll
    for (int o = 0; o < 9; ++o) {
        const int ny = clampi(cy + DYO[o], 0, 31);
        const int nx = clampi(cx + DXO[o], 0, 31);
        const int si = __builtin_amdgcn_readfirstlane((b << 10) + (ny << 5) + nx);
        const float* sp = seeds + (size_t)si * NC;  // uniform -> s_load
        float ip = 0.f;
#pragma unroll
        for (int c = 0; c < NC; ++c) ip += xv[c] * sp[c];
        d[o] = snorm[si] - 2.0f * ip;
    }
    float m = d[0];
#pragma unroll
    for (int o = 1; o < 9; ++o) m = fminf(m, d[o]);
    float w[9];
    float wsum = 0.f;
#pragma unroll
    for (int o = 0; o < 9; ++o) {
        w[o] = __expf(m - d[o]);
        wsum += w[o];
    }
    const float inv = 1.0f / wsum;
#pragma unroll
    for (int o = 0; o < 9; ++o) qs[(o << 8) + t] = w[o] * inv;
    __syncthreads();

    // ---- phase 2: all 4 waves, register-tiled 21x9 reduction ----
    const int wid = t >> 6, tl = t & 63;
    if (tl < 56) {
        const int cg = tl >> 3, s = tl & 7;
        const int r0 = cg * 3;
        float acc[3][9];
#pragma unroll
        for (int j = 0; j < 3; ++j)
#pragma unroll
            for (int o = 0; o < 9; ++o) acc[j][o] = 0.f;

#pragma unroll
        for (int kk = 0; kk < 2; ++kk) {
            const int q = (((wid << 1) + kk) << 3) + s;   // quad id 0..63
            const float* xr = xb + (q >> 2) * NW + ((q & 3) << 2);
            const float4 x0 = *reinterpret_cast<const float4*>(xr + (size_t)(r0 + 0) * HW);
            const float4 x1 = *reinterpret_cast<const float4*>(xr + (size_t)(r0 + 1) * HW);
            float4 x2 = make_float4(1.f, 1.f, 1.f, 1.f);
            if (cg < 6)
                x2 = *reinterpret_cast<const float4*>(xr + (size_t)(r0 + 2) * HW);
#pragma unroll
            for (int o = 0; o < 9; ++o) {
                const float4 q4 = *reinterpret_cast<const float4*>(&qs[(o << 8) + (q << 2)]);
                acc[0][o] += q4.x * x0.x + q4.y * x0.y + q4.z * x0.z + q4.w * x0.w;
                acc[1][o] += q4.x * x1.x + q4.y * x1.y + q4.z * x1.z + q4.w * x1.w;
                acc[2][o] += q4.x * x2.x + q4.y * x2.y + q4.z * x2.z + q4.w * x2.w;
            }
        }
        // fold the 8 strips (s = lane bits 0..2)
#pragma unroll
        for (int j = 0; j < 3; ++j)
#pragma unroll
            for (int o = 0; o < 9; ++o) {
                acc[j][o] += __shfl_xor(acc[j][o], 1, 64);
                acc[j][o] += __shfl_xor(acc[j][o], 2, 64);
                acc[j][o] += __shfl_xor(acc[j][o], 4, 64);
            }
        if (s == 0) {
#pragma unroll
            for (int o = 0; o < 9; ++o)
#pragma unroll
                for (int j = 0; j < 3; ++j)
                    pbuf[wid * 216 + o * 24 + r0 + j] = acc[j][o];
        }
    }
    __syncthreads();

    // ---- cross-wave sum + one contiguous non-atomic store ----
    if (t < PART_STRIDE) {
        const int o = t / 21, c = t - o * 21;
        const float v = pbuf[o * 24 + c] + pbuf[216 + o * 24 + c]
                      + pbuf[432 + o * 24 + c] + pbuf[648 + o * 24 + c];
        part[(size_t)((b << 10) + cell) * PART_STRIDE + t] = v;
    }
}

// ---------------------------------------------------------------------------
// Kernel 3: gather 9-stencil partials -> seeds = num/(den+eps), snorm.
// 192 thr: t<168 = (seed-slot 0..7, ch 0..20). Always exactly 9 contributors
// per seed (per-axis: {max(s-1,0), s, min(s+1,31)} with edge-adjusted deltas).
// ---------------------------------------------------------------------------
__global__ __launch_bounds__(192) void k_divz(const float* __restrict__ part,
                                              float* __restrict__ seeds,
                                              float* __restrict__ snorm) {
    __shared__ float den[8];
    __shared__ float sq[8][20];
    const int t = threadIdx.x;
    const int sl = t / 21, c = t - sl * 21;   // valid for t<168
    const int sid = blockIdx.x * 8 + sl;

    float tot = 0.f;
    if (t < 168) {
        const int b = sid >> 10;
        const int s1 = sid & 1023;
        const int sy = s1 >> 5, sx = s1 & 31;

        int cys[3], dys[3], cxs[3], dxs[3];
        cys[0] = sy > 0 ? sy - 1 : 0;   dys[0] = (sy == 0) ? -1 : 1;
        cys[1] = sy;                    dys[1] = 0;
        cys[2] = sy < 31 ? sy + 1 : 31; dys[2] = (sy == 31) ? 1 : -1;
        cxs[0] = sx > 0 ? sx - 1 : 0;   dxs[0] = (sx == 0) ? -1 : 1;
        cxs[1] = sx;                    dxs[1] = 0;
        cxs[2] = sx < 31 ? sx + 1 : 31; dxs[2] = (sx == 31) ? 1 : -1;

#pragma unroll
        for (int jy = 0; jy < 3; ++jy)
#pragma unroll
            for (int jx = 0; jx < 3; ++jx) {
                const int cell = (b << 10) + (cys[jy] << 5) + cxs[jx];
                const int o = (dys[jy] + 1) * 3 + (dxs[jx] + 1);
                tot += part[(size_t)cell * PART_STRIDE + o * 21 + c];
            }
        if (c == 20) den[sl] = tot;
    }
    __syncthreads();
    if (t < 168 && c < 20) {
        const float v = tot / (den[sl] + EPSF);
        seeds[(size_t)sid * NC + c] = v;
        sq[sl][c] = v * v;
    }
    __syncthreads();
    if (t < 8) {
        float n = 0.f;
#pragma unroll
        for (int cc = 0; cc < NC; ++cc) n += sq[t][cc];
        snorm[blockIdx.x * 8 + t] = n;
    }
}

// ---------------------------------------------------------------------------
// Kernel 4: final assignment pass -> write Q (B, 9, H, W). No LDS, no barriers.
// ---------------------------------------------------------------------------
__global__ __launch_bounds__(256, 8) void k_final(const float* __restrict__ x,
                                                  const float* __restrict__ seeds,
                                                  const float* __restrict__ snorm,
                                                  float* __restrict__ out) {
    const int t = threadIdx.x;
    const int cell = xcd_cell(blockIdx.x);
    const int b = blockIdx.y;
    const int cy = cell >> 5, cx = cell & 31;

    const int py = (cy << 4) + (t >> 4);
    const int px = (cx << 4) + (t & 15);
    const float* xp = x + (size_t)b * (NC * HW) + (size_t)py * NW + px;
    float xv[NC];
#pragma unroll
    for (int c = 0; c < NC; ++c) xv[c] = xp[(size_t)c * HW];

    float d[9];
#pragma unroll
    for (int o = 0; o < 9; ++o) {
        const int ny = clampi(cy + DYO[o], 0, 31);
        const int nx = clampi(cx + DXO[o], 0, 31);
        const int si = __builtin_amdgcn_readfirstlane((b << 10) + (ny << 5) + nx);
        const float* sp = seeds + (size_t)si * NC;  // uniform -> s_load
        float ip = 0.f;
#pragma unroll
        for (int c = 0; c < NC; ++c) ip += xv[c] * sp[c];
        d[o] = snorm[si] - 2.0f * ip;
    }
    float m = d[0];
#pragma unroll
    for (int o = 1; o < 9; ++o) m = fminf(m, d[o]);
    float w[9];
    float wsum = 0.f;
#pragma unroll
    for (int o = 0; o < 9; ++o) {
        w[o] = __expf(m - d[o]);
        wsum += w[o];
    }
    const float inv = 1.0f / wsum;
#pragma unroll
    for (int o = 0; o < 9; ++o) {
        out[(((size_t)b * 9 + o) * NH + py) * NW + px] = w[o] * inv;
    }
}

// ---------------------------------------------------------------------------
extern "C" void kernel_launch(void* const* d_in, const int* in_sizes, int n_in,
                              void* d_out, int out_size, void* d_ws, size_t ws_size,
                              hipStream_t stream) {
    const float* x = (const float*)d_in[0];
    float* out = (float*)d_out;

    float* seeds = (float*)d_ws;                    // 163840 floats
    float* snorm = seeds + SEEDS_ELEMS;             // 8192 floats
    float* part  = snorm + SNORM_ELEMS;             // 8192*189 = 1548288 floats

    const dim3 grid(NS, NB);  // 1024 cells x 8 batches
    k_seed_init<<<grid, 160, 0, stream>>>(x, seeds, snorm);

    for (int it = 0; it < 3; ++it) {
        k_iter<<<grid, 256, 0, stream>>>(x, seeds, snorm, part);
        k_divz<<<NB * NS / 8, 192, 0, stream>>>(part, seeds, snorm);
    }
    k_final<<<grid, 256, 0, stream>>>(x, seeds, snorm, out);
}

// Round 5
// 447.862 us; speedup vs baseline: 2.1163x; 1.4430x over previous
//
#include <hip/hip_runtime.h>

// LatticeSuperpixel: B=8, C=20, H=W=512, 32x32 seeds, 16x16 cells, 4 levels.
//
// R4: R3 structure + SPILL FIX.
//  R3 post-mortem: __launch_bounds__(256,8) capped VGPR at 64; phase 1 needs
//  ~45+ live regs (xv[20]+d[9]+w[9]+addr) -> compiler allocated 32 and
//  spilled to scratch = HBM traffic: WRITE_SIZE 205 MB (vs 6.2 MB of real
//  writes), FETCH 266 MB (vs ~175 MB compulsory). Kernel paced at HBM:
//  483 MB / 4 TB/s = 118 us. Fix: __launch_bounds__(256,4) (128-VGPR cap;
//  R1's identical phase-1 compiled to 44 VGPR, no spill).
//  Kept from R3: zero atomics (part[cell][9][21] contiguous 756B store +
//  9-point stencil gather in k_divz); no x LDS staging; scalar-path seeds;
//  4-wave phase 2; XCD cell swizzle.
#define NB 8
#define NC 20
#define NH 512
#define NW 512
#define NS 1024           // 32*32 seeds
#define HW (NH * NW)
#define SEEDS_ELEMS (NB * NS * NC)   // 163840
#define SNORM_ELEMS (NB * NS)        // 8192
#define PART_STRIDE 189              // 9 offsets * 21 channels
#define EPSF 1e-8f

static constexpr int DYO[9] = {-1, -1, -1, 0, 0, 0, 1, 1, 1};
static constexpr int DXO[9] = {-1, 0, 1, -1, 0, 1, -1, 0, 1};

__device__ __forceinline__ int clampi(int v, int lo, int hi) {
    return v < lo ? lo : (v > hi ? hi : v);
}

// 1024 cells -> 128 consecutive cells per XCD (bijective).
__device__ __forceinline__ int xcd_cell(int bx) {
    return ((bx & 7) << 7) + (bx >> 3);
}

// ---------------------------------------------------------------------------
// Kernel 1: seed init = mean over each 16x16 patch, per channel + seed norm.
// ---------------------------------------------------------------------------
__global__ __launch_bounds__(160) void k_seed_init(const float* __restrict__ x,
                                                   float* __restrict__ seeds,
                                                   float* __restrict__ snorm) {
    __shared__ float sm[NC];
    const int tt = threadIdx.x;           // < 160
    const int cell = blockIdx.x;
    const int b = blockIdx.y;
    const int cy = cell >> 5, cx = cell & 31;
    const int c = tt >> 3, s = tt & 7;

    const float* xb = x + (size_t)b * (NC * HW) + (size_t)c * HW
                        + (size_t)(cy << 4) * NW + (cx << 4);
    float acc = 0.f;
#pragma unroll
    for (int k = 0; k < 8; ++k) {
        const int row = (k << 1) + (s >> 2);
        const int col = (s & 3) << 2;
        const float4 v = *reinterpret_cast<const float4*>(xb + row * NW + col);
        acc += v.x + v.y + v.z + v.w;
    }
    acc += __shfl_xor(acc, 1, 64);
    acc += __shfl_xor(acc, 2, 64);
    acc += __shfl_xor(acc, 4, 64);
    if (s == 0) {
        const float mv = acc * (1.0f / 256.0f);
        seeds[((size_t)(b << 10) + cell) * NC + c] = mv;
        sm[c] = mv;
    }
    __syncthreads();
    if (tt == 0) {
        float n = 0.f;
#pragma unroll
        for (int cc = 0; cc < NC; ++cc) n += sm[cc] * sm[cc];
        snorm[(b << 10) + cell] = n;
    }
}

// ---------------------------------------------------------------------------
// Kernel 2: one assignment iteration -> per-(cell,offset) partials.
// Phase 1: 256 thr = 1 pixel: 20 global loads, dist vs 9 seeds (scalar-path),
//          softmax -> qs (LDS).
// Phase 2: all 4 waves; wave w owns pixel-strips {2w,2w+1}; thread (cg<7,s<8)
//          = channels {3cg..3cg+2} (c==20 -> ones/denom); shfl fold; per-wave
//          partials -> pbuf (LDS); cross-wave sum; ONE contiguous 756B
//          non-atomic store of part[cell][189]. Zero atomics.
// ---------------------------------------------------------------------------
__global__ __launch_bounds__(256, 4) void k_iter(const float* __restrict__ x,
                                                 const float* __restrict__ seeds,
                                                 const float* __restrict__ snorm,
                                                 float* __restrict__ part) {
    __shared__ __align__(16) float qs[9 * 256];     // [offset][pixel] 9.2 KB
    __shared__ float pbuf[4 * 9 * 24];              // [wave][offset][ch pad24] 3.5 KB

    const int t = threadIdx.x;
    const int cell = xcd_cell(blockIdx.x);
    const int b = blockIdx.y;
    const int cy = cell >> 5, cx = cell & 31;

    const float* xb = x + (size_t)b * (NC * HW) + (size_t)(cy << 4) * NW + (cx << 4);

    // ---- phase 1: own pixel's 20 channels global -> reg ----
    const float* xp = xb + (t >> 4) * NW + (t & 15);
    float xv[NC];
#pragma unroll
    for (int c = 0; c < NC; ++c) xv[c] = xp[(size_t)c * HW];

    float d[9];
#pragma unroll
    for (int o = 0; o < 9; ++o) {
        const int ny = clampi(cy + DYO[o], 0, 31);
        const int nx = clampi(cx + DXO[o], 0, 31);
        const int si = __builtin_amdgcn_readfirstlane((b << 10) + (ny << 5) + nx);
        const float* sp = seeds + (size_t)si * NC;  // uniform -> s_load
        float ip = 0.f;
#pragma unroll
        for (int c = 0; c < NC; ++c) ip += xv[c] * sp[c];
        d[o] = snorm[si] - 2.0f * ip;
    }
    float m = d[0];
#pragma unroll
    for (int o = 1; o < 9; ++o) m = fminf(m, d[o]);
    float w[9];
    float wsum = 0.f;
#pragma unroll
    for (int o = 0; o < 9; ++o) {
        w[o] = __expf(m - d[o]);
        wsum += w[o];
    }
    const float inv = 1.0f / wsum;
#pragma unroll
    for (int o = 0; o < 9; ++o) qs[(o << 8) + t] = w[o] * inv;
    __syncthreads();

    // ---- phase 2: all 4 waves, register-tiled 21x9 reduction ----
    const int wid = t >> 6, tl = t & 63;
    if (tl < 56) {
        const int cg = tl >> 3, s = tl & 7;
        const int r0 = cg * 3;
        float acc[3][9];
#pragma unroll
        for (int j = 0; j < 3; ++j)
#pragma unroll
            for (int o = 0; o < 9; ++o) acc[j][o] = 0.f;

#pragma unroll
        for (int kk = 0; kk < 2; ++kk) {
            const int q = (((wid << 1) + kk) << 3) + s;   // quad id 0..63
            const float* xr = xb + (q >> 2) * NW + ((q & 3) << 2);
            const float4 x0 = *reinterpret_cast<const float4*>(xr + (size_t)(r0 + 0) * HW);
            const float4 x1 = *reinterpret_cast<const float4*>(xr + (size_t)(r0 + 1) * HW);
            float4 x2 = make_float4(1.f, 1.f, 1.f, 1.f);
            if (cg < 6)
                x2 = *reinterpret_cast<const float4*>(xr + (size_t)(r0 + 2) * HW);
#pragma unroll
            for (int o = 0; o < 9; ++o) {
                const float4 q4 = *reinterpret_cast<const float4*>(&qs[(o << 8) + (q << 2)]);
                acc[0][o] += q4.x * x0.x + q4.y * x0.y + q4.z * x0.z + q4.w * x0.w;
                acc[1][o] += q4.x * x1.x + q4.y * x1.y + q4.z * x1.z + q4.w * x1.w;
                acc[2][o] += q4.x * x2.x + q4.y * x2.y + q4.z * x2.z + q4.w * x2.w;
            }
        }
        // fold the 8 strips (s = lane bits 0..2)
#pragma unroll
        for (int j = 0; j < 3; ++j)
#pragma unroll
            for (int o = 0; o < 9; ++o) {
                acc[j][o] += __shfl_xor(acc[j][o], 1, 64);
                acc[j][o] += __shfl_xor(acc[j][o], 2, 64);
                acc[j][o] += __shfl_xor(acc[j][o], 4, 64);
            }
        if (s == 0) {
#pragma unroll
            for (int o = 0; o < 9; ++o)
#pragma unroll
                for (int j = 0; j < 3; ++j)
                    pbuf[wid * 216 + o * 24 + r0 + j] = acc[j][o];
        }
    }
    __syncthreads();

    // ---- cross-wave sum + one contiguous non-atomic store ----
    if (t < PART_STRIDE) {
        const int o = t / 21, c = t - o * 21;
        const float v = pbuf[o * 24 + c] + pbuf[216 + o * 24 + c]
                      + pbuf[432 + o * 24 + c] + pbuf[648 + o * 24 + c];
        part[(size_t)((b << 10) + cell) * PART_STRIDE + t] = v;
    }
}

// ---------------------------------------------------------------------------
// Kernel 3: gather 9-stencil partials -> seeds = num/(den+eps), snorm.
// 192 thr: t<168 = (seed-slot 0..7, ch 0..20). Always exactly 9 contributors
// per seed (per-axis: {max(s-1,0), s, min(s+1,31)} with edge-adjusted deltas).
// ---------------------------------------------------------------------------
__global__ __launch_bounds__(192) void k_divz(const float* __restrict__ part,
                                              float* __restrict__ seeds,
                                              float* __restrict__ snorm) {
    __shared__ float den[8];
    __shared__ float sq[8][20];
    const int t = threadIdx.x;
    const int sl = t / 21, c = t - sl * 21;   // valid for t<168
    const int sid = blockIdx.x * 8 + sl;

    float tot = 0.f;
    if (t < 168) {
        const int b = sid >> 10;
        const int s1 = sid & 1023;
        const int sy = s1 >> 5, sx = s1 & 31;

        int cys[3], dys[3], cxs[3], dxs[3];
        cys[0] = sy > 0 ? sy - 1 : 0;   dys[0] = (sy == 0) ? -1 : 1;
        cys[1] = sy;                    dys[1] = 0;
        cys[2] = sy < 31 ? sy + 1 : 31; dys[2] = (sy == 31) ? 1 : -1;
        cxs[0] = sx > 0 ? sx - 1 : 0;   dxs[0] = (sx == 0) ? -1 : 1;
        cxs[1] = sx;                    dxs[1] = 0;
        cxs[2] = sx < 31 ? sx + 1 : 31; dxs[2] = (sx == 31) ? 1 : -1;

#pragma unroll
        for (int jy = 0; jy < 3; ++jy)
#pragma unroll
            for (int jx = 0; jx < 3; ++jx) {
                const int cell = (b << 10) + (cys[jy] << 5) + cxs[jx];
                const int o = (dys[jy] + 1) * 3 + (dxs[jx] + 1);
                tot += part[(size_t)cell * PART_STRIDE + o * 21 + c];
            }
        if (c == 20) den[sl] = tot;
    }
    __syncthreads();
    if (t < 168 && c < 20) {
        const float v = tot / (den[sl] + EPSF);
        seeds[(size_t)sid * NC + c] = v;
        sq[sl][c] = v * v;
    }
    __syncthreads();
    if (t < 8) {
        float n = 0.f;
#pragma unroll
        for (int cc = 0; cc < NC; ++cc) n += sq[t][cc];
        snorm[blockIdx.x * 8 + t] = n;
    }
}

// ---------------------------------------------------------------------------
// Kernel 4: final assignment pass -> write Q (B, 9, H, W). No LDS, no barriers.
// ---------------------------------------------------------------------------
__global__ __launch_bounds__(256, 4) void k_final(const float* __restrict__ x,
                                                  const float* __restrict__ seeds,
                                                  const float* __restrict__ snorm,
                                                  float* __restrict__ out) {
    const int t = threadIdx.x;
    const int cell = xcd_cell(blockIdx.x);
    const int b = blockIdx.y;
    const int cy = cell >> 5, cx = cell & 31;

    const int py = (cy << 4) + (t >> 4);
    const int px = (cx << 4) + (t & 15);
    const float* xp = x + (size_t)b * (NC * HW) + (size_t)py * NW + px;
    float xv[NC];
#pragma unroll
    for (int c = 0; c < NC; ++c) xv[c] = xp[(size_t)c * HW];

    float d[9];
#pragma unroll
    for (int o = 0; o < 9; ++o) {
        const int ny = clampi(cy + DYO[o], 0, 31);
        const int nx = clampi(cx + DXO[o], 0, 31);
        const int si = __builtin_amdgcn_readfirstlane((b << 10) + (ny << 5) + nx);
        const float* sp = seeds + (size_t)si * NC;  // uniform -> s_load
        float ip = 0.f;
#pragma unroll
        for (int c = 0; c < NC; ++c) ip += xv[c] * sp[c];
        d[o] = snorm[si] - 2.0f * ip;
    }
    float m = d[0];
#pragma unroll
    for (int o = 1; o < 9; ++o) m = fminf(m, d[o]);
    float w[9];
    float wsum = 0.f;
#pragma unroll
    for (int o = 0; o < 9; ++o) {
        w[o] = __expf(m - d[o]);
        wsum += w[o];
    }
    const float inv = 1.0f / wsum;
#pragma unroll
    for (int o = 0; o < 9; ++o) {
        out[(((size_t)b * 9 + o) * NH + py) * NW + px] = w[o] * inv;
    }
}

// ---------------------------------------------------------------------------
extern "C" void kernel_launch(void* const* d_in, const int* in_sizes, int n_in,
                              void* d_out, int out_size, void* d_ws, size_t ws_size,
                              hipStream_t stream) {
    const float* x = (const float*)d_in[0];
    float* out = (float*)d_out;

    float* seeds = (float*)d_ws;                    // 163840 floats
    float* snorm = seeds + SEEDS_ELEMS;             // 8192 floats
    float* part  = snorm + SNORM_ELEMS;             // 8192*189 = 1548288 floats

    const dim3 grid(NS, NB);  // 1024 cells x 8 batches
    k_seed_init<<<grid, 160, 0, stream>>>(x, seeds, snorm);

    for (int it = 0; it < 3; ++it) {
        k_iter<<<grid, 256, 0, stream>>>(x, seeds, snorm, part);
        k_divz<<<NB * NS / 8, 192, 0, stream>>>(part, seeds, snorm);
    }
    k_final<<<grid, 256, 0, stream>>>(x, seeds, snorm, out);
}